// Round 13
// baseline (530.452 us; speedup 1.0000x reference)
//
#include <hip/hip_runtime.h>
#include <hip/hip_fp16.h>
#include <stdint.h>

#define NN 50000
#define NE 800000
#define SCAN_BLOCKS 196   // 196*256 = 50176 >= NN

typedef _Float16 half8v __attribute__((ext_vector_type(8)));
typedef float f32x4 __attribute__((ext_vector_type(4)));

static __device__ __forceinline__ __half2 u2h2(unsigned int u) {
    union { unsigned int u; __half2 h; } c; c.u = u; return c.h;
}
static __device__ __forceinline__ unsigned int h22u(__half2 h) {
    union { __half2 h; unsigned int u; } c; c.h = h; return c.u;
}
static __device__ __forceinline__ float us2f(unsigned short s) {
    union { unsigned short s; __half h; } c; c.s = s; return __half2float(c.h);
}
static __device__ __forceinline__ unsigned short f2us(float f) {
    union { __half h; unsigned short s; } c; c.h = __float2half(f); return c.s;
}

static __device__ __forceinline__ float4 fma4(float4 a, float s, float4 w) {
    a.x = fmaf(s, w.x, a.x); a.y = fmaf(s, w.y, a.y);
    a.z = fmaf(s, w.z, a.z); a.w = fmaf(s, w.w, a.w);
    return a;
}
// acc[8] += relu(h + e); h/e = 16B of packed fp16, math in fp32
static __device__ __forceinline__ void acc8(float* acc, float4 hv, float4 ev) {
    const unsigned int* hu = (const unsigned int*)&hv;
    const unsigned int* eu = (const unsigned int*)&ev;
    #pragma unroll
    for (int q = 0; q < 4; ++q) {
        float2 hf = __half22float2(u2h2(hu[q]));
        float2 ef = __half22float2(u2h2(eu[q]));
        acc[q * 2]     += fmaxf(hf.x + ef.x, 0.f);
        acc[q * 2 + 1] += fmaxf(hf.y + ef.y, 0.f);
    }
}

// ---------- CSR build ----------
__global__ __launch_bounds__(256) void k_deg(const int* __restrict__ ei, int* __restrict__ offcur) {
    int e = blockIdx.x * 256 + threadIdx.x;
    atomicAdd(&offcur[ei[NE + e]], 1);
}

__global__ __launch_bounds__(256) void k_scanA(const int* __restrict__ off, int* __restrict__ part) {
    __shared__ int s[256];
    int t = threadIdx.x;
    int idx = blockIdx.x * 256 + t;
    int d = (idx < NN) ? off[idx] : 0;
    s[t] = d; __syncthreads();
    for (int o = 128; o > 0; o >>= 1) {
        if (t < o) s[t] += s[t + o];
        __syncthreads();
    }
    if (t == 0) part[blockIdx.x] = s[0];
}

__global__ __launch_bounds__(256) void k_scanB(int* __restrict__ part) {
    __shared__ int s[256];
    int t = threadIdx.x;
    int d = (t < SCAN_BLOCKS) ? part[t] : 0;
    s[t] = d; __syncthreads();
    #pragma unroll
    for (int o = 1; o < 256; o <<= 1) {
        int v = (t >= o) ? s[t - o] : 0;
        __syncthreads();
        s[t] += v;
        __syncthreads();
    }
    if (t < SCAN_BLOCKS) part[t] = s[t] - d;   // exclusive
}

__global__ __launch_bounds__(256) void k_scanC(int* __restrict__ off, const int* __restrict__ part) {
    __shared__ int s[256];
    int t = threadIdx.x;
    int idx = blockIdx.x * 256 + t;
    int d = (idx < NN) ? off[idx] : 0;
    s[t] = d; __syncthreads();
    #pragma unroll
    for (int o = 1; o < 256; o <<= 1) {
        int v = (t >= o) ? s[t - o] : 0;
        __syncthreads();
        s[t] += v;
        __syncthreads();
    }
    if (idx < NN) off[idx] = s[t] - d + part[blockIdx.x];
}

// ---------- weight prep: 9 f32 64x64 matrices -> fp16 MFMA B-fragments ----------
// blockIdx 0: ew2 ; blockIdx 1+2l: cw1[l] ; blockIdx 2+2l: cw2[l]
__global__ __launch_bounds__(256) void k_prep(const float* __restrict__ ew2,
        const float* __restrict__ cw1, const float* __restrict__ cw2,
        __half* __restrict__ wf) {
    int b = blockIdx.x;
    const float* src;
    if (b == 0) src = ew2;
    else {
        int l = (b - 1) >> 1;
        src = ((b - 1) & 1) ? (cw2 + (size_t)l * 4096) : (cw1 + (size_t)l * 4096);
    }
    __half* dst = wf + (size_t)b * 4096;
    int tid = threadIdx.x;
    for (int i = tid; i < 4096; i += 256) {
        int k = i >> 6, n = i & 63;
        int kt = k >> 5, kin = k & 31;
        int quad = kin >> 3, j = kin & 7;
        int nt = n >> 4, nin = n & 15;
        dst[(size_t)((kt * 4 + nt) * 64 + quad * 16 + nin) * 8 + j] = __float2half(src[i]);
    }
}

// ---------- h init (fp16 shadow store) ----------
__global__ __launch_bounds__(256) void k_input(const float* __restrict__ x,
        const float* __restrict__ in_w, const float* __restrict__ in_b,
        __half* __restrict__ Ah) {
    int n = blockIdx.x * 4 + (threadIdx.x >> 6);
    int k = threadIdx.x & 63;
    const float* xr = x + (size_t)n * 3;
    float v = in_b[k] + xr[0] * in_w[k] + xr[1] * in_w[64 + k] + xr[2] * in_w[128 + k];
    Ah[(size_t)n * 64 + k] = __float2half(v);
}

// ---------- edge prepass: packed CSR records {row u16, rx fp16, ry fp16, 0} ----------
__global__ __launch_bounds__(256) void k_rel(const float* __restrict__ x,
        const int* __restrict__ ei, int* __restrict__ offcur,
        ushort4* __restrict__ rec) {
    int e = blockIdx.x * 256 + threadIdx.x;
    int r = ei[e], c = ei[NE + e];
    float rx = x[(size_t)c * 3]     - x[(size_t)r * 3];
    float ry = x[(size_t)c * 3 + 1] - x[(size_t)r * 3 + 1];
    int pos = atomicAdd(&offcur[c], 1);
    ushort4 rc;
    rc.x = (unsigned short)r;
    rc.y = f2us(rx);
    rc.z = f2us(ry);
    rc.w = 0;
    rec[pos] = rc;
}

// ---------- per-layer: gather aggregate with on-the-fly edge MLP (f16 MFMA) ----------
// wave per node. Per 16-edge group: compute ea = relu(relpos@W1+b1)@W2+b2 via MFMA
// (verified k_edge fragment recipe), stage C-layout in wave-private LDS, then the
// proven es x oc gather path reads ea from LDS instead of global.
__global__ __launch_bounds__(256) void k_agg(const __half* __restrict__ Ah,
        const ushort4* __restrict__ rec, const int* __restrict__ offcur,
        const __half* __restrict__ w2f,
        const float* __restrict__ ew1, const float* __restrict__ eb1,
        const float* __restrict__ eb2,
        __half* __restrict__ M) {
    __shared__ float s_w1[128], s_b1[64], s_b2[64];
    __shared__ __half s_ea[4][16][80];     // per-wave, [edge][ch] pad 80
    const float4* A4 = (const float4*)Ah;  // 8 fp16 per float4
    int tid = threadIdx.x, lane = tid & 63, w = tid >> 6;
    int lm = lane & 15, lq = lane >> 4;
    int es = lane >> 3, oc = lane & 7;

    half8v bf[8];
    {
        const half8v* W2F = (const half8v*)w2f;
        #pragma unroll
        for (int f = 0; f < 8; ++f) bf[f] = W2F[f * 64 + lane];
    }
    if (tid < 128) s_w1[tid] = ew1[tid];
    if (tid < 64) s_b1[tid] = eb1[tid];
    else if (tid < 128) s_b2[tid - 64] = eb2[tid - 64];
    __syncthreads();

    int n = blockIdx.x * 4 + w;
    int p0 = (n == 0) ? 0 : offcur[n - 1];
    int p1 = offcur[n];
    float acc[8] = {0,0,0,0,0,0,0,0};
    float accB[8] = {0,0,0,0,0,0,0,0};

    for (int base = p0; base < p1; base += 16) {
        int cnt = min(16, p1 - base);
        ushort4 rc = rec[base + min(lm, cnt - 1)];
        int rl = (int)rc.x;
        float rx = us2f(rc.y), ry = us2f(rc.z);

        // t in A-frag layout: this lane = edge lm, k = lq*8+j (and +32)
        half8v a0, a1;
        #pragma unroll
        for (int j = 0; j < 8; ++j) {
            int k0 = lq * 8 + j;
            a0[j] = (_Float16)fmaxf(fmaf(rx, s_w1[k0], fmaf(ry, s_w1[64 + k0], s_b1[k0])), 0.f);
            int k1 = k0 + 32;
            a1[j] = (_Float16)fmaxf(fmaf(rx, s_w1[k1], fmaf(ry, s_w1[64 + k1], s_b1[k1])), 0.f);
        }
        f32x4 d[4];
        #pragma unroll
        for (int nt = 0; nt < 4; ++nt) {
            float b = s_b2[nt * 16 + lm];
            d[nt][0] = b; d[nt][1] = b; d[nt][2] = b; d[nt][3] = b;
            d[nt] = __builtin_amdgcn_mfma_f32_16x16x32_f16(a0, bf[nt],     d[nt], 0, 0, 0);
            d[nt] = __builtin_amdgcn_mfma_f32_16x16x32_f16(a1, bf[4 + nt], d[nt], 0, 0, 0);
        }
        // C-layout: row(edge)=lq*4+r, col(ch)=nt*16+lm -> wave-private LDS
        __builtin_amdgcn_wave_barrier();
        #pragma unroll
        for (int nt = 0; nt < 4; ++nt)
            #pragma unroll
            for (int r = 0; r < 4; ++r)
                s_ea[w][lq * 4 + r][nt * 16 + lm] = __float2half(d[nt][r]);
        __builtin_amdgcn_wave_barrier();

        // gather-accumulate (proven path; ea from LDS)
        int i0 = es, i1 = 8 + es;
        int ic0 = min(i0, cnt - 1), ic1 = min(i1, cnt - 1);
        int r0 = __shfl(rl, ic0, 64);
        int r1 = __shfl(rl, ic1, 64);
        float4 h0 = A4[(size_t)r0 * 8 + oc];
        float4 h1 = A4[(size_t)r1 * 8 + oc];
        float4 e0 = *(const float4*)&s_ea[w][ic0][oc * 8];
        float4 e1 = *(const float4*)&s_ea[w][ic1][oc * 8];
        if (i0 < cnt) acc8(acc, h0, e0);
        if (i1 < cnt) acc8(accB, h1, e1);
        __builtin_amdgcn_wave_barrier();   // WAR fence before next group's ds_write
    }
    #pragma unroll
    for (int q = 0; q < 8; ++q) acc[q] += accB[q];
    #pragma unroll
    for (int m = 8; m < 64; m <<= 1) {
        #pragma unroll
        for (int q = 0; q < 8; ++q) acc[q] += __shfl_xor(acc[q], m, 64);
    }
    if (es == 0) {
        float4 sv = A4[(size_t)n * 8 + oc];
        const unsigned int* su = (const unsigned int*)&sv;
        unsigned int o[4];
        #pragma unroll
        for (int q = 0; q < 4; ++q) {
            float2 sf = __half22float2(u2h2(su[q]));
            o[q] = h22u(__floats2half2_rn(sf.x + acc[q * 2], sf.y + acc[q * 2 + 1]));
        }
        *(uint4*)&M[(size_t)n * 64 + oc * 8] = *(uint4*)&o[0];
    }
}

// ---------- per-layer: node MLP via f16 MFMA + LN + gelu + residual ----------
__global__ __launch_bounds__(256) void k_node(__half* __restrict__ Ah, const __half* __restrict__ M,
        const __half* __restrict__ w1f, const __half* __restrict__ w2f,
        const float* __restrict__ cb1, const float* __restrict__ cb2,
        const float* __restrict__ lnw, const float* __restrict__ lnb) {
    __shared__ __half s_u[4][16][72];   // per-wave 16 nodes x 64 ch (pad 72)
    __shared__ float s_b1[64], s_b2[64], s_g[64], s_bt[64];
    int tid = threadIdx.x, lane = tid & 63, w = tid >> 6;
    int lm = lane & 15, lq = lane >> 4;

    half8v bw1[8], bw2[8];
    {
        const half8v* W1F = (const half8v*)w1f;
        const half8v* W2F = (const half8v*)w2f;
        #pragma unroll
        for (int f = 0; f < 8; ++f) { bw1[f] = W1F[f * 64 + lane]; bw2[f] = W2F[f * 64 + lane]; }
    }
    if (tid < 64) { s_b1[tid] = cb1[tid]; s_g[tid] = lnw[tid]; }
    else if (tid < 128) { s_b2[tid - 64] = cb2[tid - 64]; s_bt[tid - 64] = lnb[tid - 64]; }
    __syncthreads();

    int nb = blockIdx.x * 64;
    int na = nb + w * 16 + lm;
    int nac = min(na, NN - 1);

    const uint4* M4 = (const uint4*)M;
    uint4 a0u = M4[(size_t)nac * 8 + lq];
    uint4 a1u = M4[(size_t)nac * 8 + 4 + lq];
    half8v a0 = *(const half8v*)&a0u;
    half8v a1 = *(const half8v*)&a1u;

    f32x4 acc[4];
    #pragma unroll
    for (int nt = 0; nt < 4; ++nt) {
        float b = s_b1[nt * 16 + lm];
        acc[nt][0] = b; acc[nt][1] = b; acc[nt][2] = b; acc[nt][3] = b;
        acc[nt] = __builtin_amdgcn_mfma_f32_16x16x32_f16(a0, bw1[nt],     acc[nt], 0, 0, 0);
        acc[nt] = __builtin_amdgcn_mfma_f32_16x16x32_f16(a1, bw1[4 + nt], acc[nt], 0, 0, 0);
    }
    __builtin_amdgcn_wave_barrier();
    #pragma unroll
    for (int nt = 0; nt < 4; ++nt)
        #pragma unroll
        for (int r = 0; r < 4; ++r)
            s_u[w][lq * 4 + r][nt * 16 + lm] = __float2half(fmaxf(acc[nt][r], 0.f));
    __builtin_amdgcn_wave_barrier();

    half8v u0 = *(const half8v*)&s_u[w][lm][lq * 8];
    half8v u1 = *(const half8v*)&s_u[w][lm][32 + lq * 8];
    #pragma unroll
    for (int nt = 0; nt < 4; ++nt) {
        float b = s_b2[nt * 16 + lm];
        acc[nt][0] = b; acc[nt][1] = b; acc[nt][2] = b; acc[nt][3] = b;
        acc[nt] = __builtin_amdgcn_mfma_f32_16x16x32_f16(u0, bw2[nt],     acc[nt], 0, 0, 0);
        acc[nt] = __builtin_amdgcn_mfma_f32_16x16x32_f16(u1, bw2[4 + nt], acc[nt], 0, 0, 0);
    }

    float S[4], SQ[4];
    #pragma unroll
    for (int r = 0; r < 4; ++r) {
        S[r]  = acc[0][r] + acc[1][r] + acc[2][r] + acc[3][r];
        SQ[r] = acc[0][r] * acc[0][r] + acc[1][r] * acc[1][r]
              + acc[2][r] * acc[2][r] + acc[3][r] * acc[3][r];
    }
    #pragma unroll
    for (int m = 1; m < 16; m <<= 1) {
        #pragma unroll
        for (int r = 0; r < 4; ++r) {
            S[r]  += __shfl_xor(S[r], m, 64);
            SQ[r] += __shfl_xor(SQ[r], m, 64);
        }
    }
    __builtin_amdgcn_wave_barrier();
    #pragma unroll
    for (int r = 0; r < 4; ++r) {
        float mu  = S[r] * (1.f / 64.f);
        float var = SQ[r] * (1.f / 64.f) - mu * mu;
        float rs  = rsqrtf(var + 1e-5f);
        #pragma unroll
        for (int nt = 0; nt < 4; ++nt) {
            int c = nt * 16 + lm;
            float y = (acc[nt][r] - mu) * rs * s_g[c] + s_bt[c];
            float ge = 0.5f * y * (1.f + erff(y * 0.70710678118654752f));
            s_u[w][lq * 4 + r][c] = __float2half(ge);
        }
    }
    __builtin_amdgcn_wave_barrier();

    #pragma unroll
    for (int it = 0; it < 2; ++it) {
        int ck = lq + 4 * it;
        int n = nb + w * 16 + lm;
        if (n < NN) {
            uint4 ge8 = *(const uint4*)&s_u[w][lm][ck * 8];
            uint4 id8 = *(const uint4*)&Ah[(size_t)n * 64 + ck * 8];
            const unsigned int* gu = (const unsigned int*)&ge8;
            const unsigned int* iu = (const unsigned int*)&id8;
            unsigned int o[4];
            #pragma unroll
            for (int p = 0; p < 4; ++p) {
                float2 gf = __half22float2(u2h2(gu[p]));
                float2 iff = __half22float2(u2h2(iu[p]));
                o[p] = h22u(__floats2half2_rn(gf.x + iff.x, gf.y + iff.y));
            }
            *(uint4*)&Ah[(size_t)n * 64 + ck * 8] = *(uint4*)&o[0];
        }
    }
}

// ---------- final: out = LN(h@(fw+rw) + (fb+rb); ow, ob) ----------
__global__ __launch_bounds__(256) void k_final(const __half* __restrict__ Ah,
        const float* __restrict__ fw, const float* __restrict__ fb,
        const float* __restrict__ rw, const float* __restrict__ rb,
        const float* __restrict__ ow, const float* __restrict__ ob,
        float* __restrict__ out) {
    __shared__ float s_W[64 * 128];     // [k][c] row-major, combined fw+rw
    __shared__ float s_h[32 * 68];
    __shared__ float s_b[128];
    __shared__ float s_red[32][4];
    int tid = threadIdx.x;
    for (int i = tid; i < 8192; i += 256) s_W[i] = fw[i] + rw[i];
    if (tid < 128) s_b[tid] = fb[tid] + rb[tid];
    int nb = blockIdx.x * 32;
    for (int i = tid; i < 2048; i += 256) {
        int nl = i >> 6, k = i & 63;
        int n = nb + nl;
        s_h[nl * 68 + k] = (n < NN) ? __half2float(Ah[(size_t)n * 64 + k]) : 0.f;
    }
    __syncthreads();

    int lane = tid & 63, w = tid >> 6;
    int chh = w & 1, nh = w >> 1;
    int cq = lane & 15, ng = lane >> 4;
    int c0 = chh * 64 + cq * 4;
    int rbase = nh * 16 + ng * 4;

    float4 acc[4];
    {
        float4 bq = *(const float4*)&s_b[c0];
        acc[0] = bq; acc[1] = bq; acc[2] = bq; acc[3] = bq;
    }
    #pragma unroll 4
    for (int k4 = 0; k4 < 16; ++k4) {
        float4 m0 = *(const float4*)&s_h[(rbase + 0) * 68 + k4 * 4];
        float4 m1 = *(const float4*)&s_h[(rbase + 1) * 68 + k4 * 4];
        float4 m2 = *(const float4*)&s_h[(rbase + 2) * 68 + k4 * 4];
        float4 m3 = *(const float4*)&s_h[(rbase + 3) * 68 + k4 * 4];
        #pragma unroll
        for (int kk = 0; kk < 4; ++kk) {
            float4 w4 = *(const float4*)&s_W[(k4 * 4 + kk) * 128 + c0];
            acc[0] = fma4(acc[0], ((const float*)&m0)[kk], w4);
            acc[1] = fma4(acc[1], ((const float*)&m1)[kk], w4);
            acc[2] = fma4(acc[2], ((const float*)&m2)[kk], w4);
            acc[3] = fma4(acc[3], ((const float*)&m3)[kk], w4);
        }
    }
    #pragma unroll
    for (int j = 0; j < 4; ++j) {
        float4 v = acc[j];
        float sum = v.x + v.y + v.z + v.w;
        float sq  = v.x * v.x + v.y * v.y + v.z * v.z + v.w * v.w;
        #pragma unroll
        for (int m = 1; m < 16; m <<= 1) {
            sum += __shfl_xor(sum, m, 64);
            sq  += __shfl_xor(sq, m, 64);
        }
        if (cq == 0) {
            s_red[rbase + j][chh * 2]     = sum;
            s_red[rbase + j][chh * 2 + 1] = sq;
        }
    }
    __syncthreads();
    float4 gq = *(const float4*)&ow[c0];
    float4 bq = *(const float4*)&ob[c0];
    #pragma unroll
    for (int j = 0; j < 4; ++j) {
        int nl = rbase + j;
        int n = nb + nl;
        float tsum = s_red[nl][0] + s_red[nl][2];
        float tsq  = s_red[nl][1] + s_red[nl][3];
        float mu  = tsum * (1.f / 128.f);
        float var = tsq * (1.f / 128.f) - mu * mu;
        float rs  = rsqrtf(var + 1e-5f);
        if (n < NN) {
            float4 v = acc[j];
            float4 o;
            o.x = (v.x - mu) * rs * gq.x + bq.x;
            o.y = (v.y - mu) * rs * gq.y + bq.y;
            o.z = (v.z - mu) * rs * gq.z + bq.z;
            o.w = (v.w - mu) * rs * gq.w + bq.w;
            *(float4*)&out[(size_t)n * 128 + c0] = o;
        }
    }
}

extern "C" void kernel_launch(void* const* d_in, const int* in_sizes, int n_in,
                              void* d_out, int out_size, void* d_ws, size_t ws_size,
                              hipStream_t stream) {
    const float* x    = (const float*)d_in[0];
    const int*   ei   = (const int*)d_in[1];
    const float* in_w = (const float*)d_in[2];
    const float* in_b = (const float*)d_in[3];
    const float* ew1  = (const float*)d_in[4];
    const float* eb1  = (const float*)d_in[5];
    const float* ew2  = (const float*)d_in[6];
    const float* eb2  = (const float*)d_in[7];
    const float* cw1  = (const float*)d_in[8];
    const float* cb1  = (const float*)d_in[9];
    const float* cw2  = (const float*)d_in[10];
    const float* cb2  = (const float*)d_in[11];
    const float* lnw  = (const float*)d_in[12];
    const float* lnb  = (const float*)d_in[13];
    const float* fw   = (const float*)d_in[14];
    const float* fb   = (const float*)d_in[15];
    const float* rw   = (const float*)d_in[16];
    const float* rb   = (const float*)d_in[17];
    const float* ow   = (const float*)d_in[18];
    const float* ob   = (const float*)d_in[19];
    float* out = (float*)d_out;

    // workspace layout (bytes) — total ~19.5 MB (fully L2/L3 resident):
    //   rec  (u16x4): NE*8    =   6,400,000  @ 0
    //   Ah   (fp16): NN*64*2  =   6,400,000  @ 6,400,000
    //   off        : (NN+1)*4 =     200,016  @ 12,800,000
    //   M    (fp16): NN*64*2  =   6,400,000  @ 13,000,016
    //   wf   (fp16): 9*4096*2 =      73,728  @ 19,400,016
    //   part : SCAN_BLOCKS*4 aliases M (dead before layer loop)
    char* ws = (char*)d_ws;
    ushort4*        rec  = (ushort4*)ws;
    __half*         Ah   = (__half*)(ws + 6400000);
    int*            off  = (int*)(ws + 12800000);
    __half*         M    = (__half*)(ws + 13000016);
    __half*         wf   = (__half*)(ws + 19400016);
    int*            part = (int*)M;

    (void)hipMemsetAsync(off, 0, (NN + 1) * sizeof(int), stream);
    k_deg<<<NE / 256, 256, 0, stream>>>(ei, off);
    k_scanA<<<SCAN_BLOCKS, 256, 0, stream>>>(off, part);
    k_scanB<<<1, 256, 0, stream>>>(part);
    k_scanC<<<SCAN_BLOCKS, 256, 0, stream>>>(off, part);
    k_prep<<<9, 256, 0, stream>>>(ew2, cw1, cw2, wf);
    k_input<<<NN / 4, 256, 0, stream>>>(x, in_w, in_b, Ah);
    k_rel<<<NE / 256, 256, 0, stream>>>(x, ei, off, rec);

    const int nodeBlocks = (NN + 63) / 64;     // 782
    for (int l = 0; l < 4; ++l) {
        k_agg<<<NN / 4, 256, 0, stream>>>(Ah, rec, off, wf, ew1, eb1, eb2, M);
        k_node<<<nodeBlocks, 256, 0, stream>>>(Ah, M,
            wf + (size_t)(1 + 2 * l) * 4096, wf + (size_t)(2 + 2 * l) * 4096,
            cb1 + (size_t)l * 64, cb2 + (size_t)l * 64,
            lnw + (size_t)l * 64, lnb + (size_t)l * 64);
    }
    k_final<<<(NN + 31) / 32, 256, 0, stream>>>(Ah, fw, fb, rw, rb, ow, ob, out);
}